// Round 5
// baseline (309.661 us; speedup 1.0000x reference)
//
#include <hip/hip_runtime.h>

#define DIMV 96
#define CCH 24
#define NVOX (DIMV * DIMV * DIMV)        // 884736
#define WORDS (NVOX / 32)                // 27648 u32 bitmap words (valid only)
#define TOTAL_INTS (WORDS + 3 * NVOX)    // bitmap + cur/glb/tgt key arrays
#define N4I (TOTAL_INTS / 4)             // 670464 int4s (exact)
#define NZERO4 (WORDS / 4)               // 6912 (bitmap -> 0; keys -> -1)

#define FILL_V4 (NVOX * 50 / 4)          // 11,059,200 v4f dense-default stores
#define ZV4 (NVOX * 49 / 4)              // 10,838,016: [0,ZV4)=0.0 (mask+cur+glb), rest=1.0 (tgt)
#define FILL_BLOCKS (FILL_V4 / 1024)     // 10800 blocks x 256 thr x 4 stores (exact)

// Native clang vector types: __builtin_nontemporal_store requires these
// (HIP's float4/int4 are classes and get rejected).
typedef float v4f __attribute__((ext_vector_type(4)));
typedef int   v4i __attribute__((ext_vector_type(4)));

// ---------------------------------------------------------------------------
// K0: init workspace (vectorized) + mask-dtype detection (block 0).
// bool inputs may arrive as uint8 (raw numpy bool), int32, or float32:
//   int32 storage  -> words in {0,1}; float32 -> {0,0x3F800000}; uint8 -> other
// mode: 0 = uint8, 1 = int32, 2 = float32
// Keys MUST be explicitly set to -1: ws contents are unknown on the first
// (correctness) call; only the timed calls are guaranteed 0xAA-poisoned.
// ---------------------------------------------------------------------------
__global__ void init_detect_kernel(v4i* __restrict__ ws_vec,
                                   const unsigned int* __restrict__ mask_words,
                                   int* __restrict__ mode_p) {
    int i = blockIdx.x * blockDim.x + threadIdx.x;
    if (i < N4I) {
        int fill = (i < NZERO4) ? 0 : -1;
        v4i val = {fill, fill, fill, fill};
        ws_vec[i] = val;
    }
    if (blockIdx.x == 0) {
        __shared__ int s_byte, s_int, s_float;
        if (threadIdx.x == 0) { s_byte = 0; s_int = 0; s_float = 0; }
        __syncthreads();
        int flag = 0;
        for (int k = 0; k < 4; ++k) {                 // 256 thr x 4 = 1024 words
            unsigned int w = mask_words[threadIdx.x * 4 + k];
            if (w != 0u) {
                if (w == 1u)               flag |= 1;
                else if (w == 0x3F800000u) flag |= 2;
                else                       flag |= 4;
            }
        }
        if (flag & 1) atomicOr(&s_int, 1);
        if (flag & 2) atomicOr(&s_float, 1);
        if (flag & 4) atomicOr(&s_byte, 1);
        __syncthreads();
        if (threadIdx.x == 0)
            *mode_p = s_byte ? 0 : (s_float ? 2 : 1);
    }
}

__device__ __forceinline__ bool read_mask(const void* p, int i, int mode) {
    if (mode == 0) return ((const unsigned char*)p)[i] != 0;
    if (mode == 1) return ((const int*)p)[i] != 0;
    return ((const float*)p)[i] != 0.0f;
}

// ---------------------------------------------------------------------------
// K1: fused  [scatter blocks first: latency-bound, start early]
//   blocks [0, SB): current rows (grid_mask -> valid bitmap, cur_key
//     atomicMax last-wins) + target rows (tgt_key: global targets key=j,
//     current targets key=n_gtgt+k -> current beats global, later beats
//     earlier = torch cat order; o_vtgt per-row floats).
//   blocks [SB, SB+FILL_BLOCKS): streaming NT fill of dense defaults:
//     mask=0, cur=0, glb=0 (first ZV4 v4s), tgt=1.0 (rest). Disjoint from
//     scatter outputs -> no intra-kernel race.
// ---------------------------------------------------------------------------
__global__ void fill_scatter_kernel(v4f* __restrict__ out_dense,
                                    const int* __restrict__ coords,
                                    const void* __restrict__ grid_mask,
                                    const int* __restrict__ mode_p,
                                    unsigned int* __restrict__ valid_bits,
                                    int* __restrict__ cur_key,
                                    const int* __restrict__ gt_coords,
                                    const int* __restrict__ ct_coords,
                                    const int* __restrict__ origin,
                                    int* __restrict__ tgt_key,
                                    float* __restrict__ out_valid_target,
                                    int n_cur, int n_gtgt, int n_tgt, int sb) {
    if ((int)blockIdx.x >= sb) {
        int base = (blockIdx.x - sb) * 1024 + threadIdx.x;   // exact range
        v4f zero = {0.f, 0.f, 0.f, 0.f};
        v4f one  = {1.f, 1.f, 1.f, 1.f};
#pragma unroll
        for (int k = 0; k < 4; ++k) {
            int idx = base + k * 256;
            __builtin_nontemporal_store(idx < ZV4 ? zero : one, &out_dense[idx]);
        }
        return;
    }
    int i = blockIdx.x * blockDim.x + threadIdx.x;
    if (i < n_cur) {
        int x = coords[3 * i], y = coords[3 * i + 1], z = coords[3 * i + 2];
        if ((unsigned)x >= DIMV || (unsigned)y >= DIMV || (unsigned)z >= DIMV) return;
        int v = (x * DIMV + y) * DIMV + z;
        if (read_mask(grid_mask, i, *mode_p))
            atomicOr(&valid_bits[v >> 5], 1u << (v & 31));
        atomicMax(&cur_key[v], i);                     // last row wins
        return;
    }
    int j = i - n_cur;
    if (j < n_gtgt) {
        int x = gt_coords[3 * j] - origin[0];
        int y = gt_coords[3 * j + 1] - origin[1];
        int z = gt_coords[3 * j + 2] - origin[2];
        bool inb = (unsigned)x < DIMV && (unsigned)y < DIMV && (unsigned)z < DIMV;
        out_valid_target[j] = inb ? 1.0f : 0.0f;
        if (inb) atomicMax(&tgt_key[(x * DIMV + y) * DIMV + z], j);
        return;
    }
    int k = j - n_gtgt;
    if (k < n_tgt) {
        int x = ct_coords[3 * k], y = ct_coords[3 * k + 1], z = ct_coords[3 * k + 2];
        if ((unsigned)x < DIMV && (unsigned)y < DIMV && (unsigned)z < DIMV)
            atomicMax(&tgt_key[(x * DIMV + y) * DIMV + z], n_gtgt + k);
    }
}

// ---------------------------------------------------------------------------
// K2: global rows: shift by origin, in-bounds, gather visibility bit (110 KB
// bitmap, hot in every XCD L2), write per-row valid/near floats, glb_key.
// ---------------------------------------------------------------------------
__global__ void scatter_global_kernel(const int* __restrict__ gcoords,
                                      const int* __restrict__ origin,
                                      const unsigned int* __restrict__ valid_bits,
                                      int* __restrict__ glb_key,
                                      float* __restrict__ out_valid,
                                      float* __restrict__ out_near,
                                      int n) {
    int i = blockIdx.x * blockDim.x + threadIdx.x;
    if (i >= n) return;
    int x = gcoords[3 * i]     - origin[0];
    int y = gcoords[3 * i + 1] - origin[1];
    int z = gcoords[3 * i + 2] - origin[2];
    bool inb = (unsigned)x < DIMV && (unsigned)y < DIMV && (unsigned)z < DIMV;
    bool valid = false;
    if (inb) {
        int v = (x * DIMV + y) * DIMV + z;
        valid = (valid_bits[v >> 5] >> (v & 31)) & 1u;
        if (valid) atomicMax(&glb_key[v], i);
    }
    out_valid[i] = valid ? 1.0f : 0.0f;
    out_near[i]  = (inb && !valid) ? 1.0f : 0.0f;
}

// ---------------------------------------------------------------------------
// K3: winner writes (row-parallel, one thread per input row):
//   cur rows:  occ -> mask=1 (benign same-value race); winner (cur_key==i)
//              copies its 96-B row into out_cur (6 NT dwordx4).
//   glb rows:  o_valid[j] (from K2) -> mask=1; winner copies into out_glb.
//              Any valid writer implies nonzero Gaussian row at v, so
//              mask = (global_volume!=0).any(-1) == "some valid row" exactly.
//   gtgt rows: winner (tgt_key==j) writes o_tgt.
//   tgt rows:  winner (tgt_key==n_gtgt+k) writes o_tgt.
// Defaults were pre-filled by K1; only sparse non-defaults touched here.
// ---------------------------------------------------------------------------
__global__ void winners_kernel(const v4f* __restrict__ cur_vals4,
                               const v4f* __restrict__ glb_vals4,
                               const int* __restrict__ coords,
                               const int* __restrict__ gcoords,
                               const int* __restrict__ gt_coords,
                               const int* __restrict__ ct_coords,
                               const float* __restrict__ tsdf_tgt,
                               const float* __restrict__ g_tsdf_tgt,
                               const void* __restrict__ occupancy,
                               const int* __restrict__ mode_p,
                               const int* __restrict__ origin,
                               const int* __restrict__ cur_key,
                               const int* __restrict__ glb_key,
                               const int* __restrict__ tgt_key,
                               const float* __restrict__ o_valid,
                               float* __restrict__ out_mask,
                               v4f* __restrict__ out_cur4,
                               v4f* __restrict__ out_glb4,
                               float* __restrict__ out_tgt,
                               int n_cur, int n_glb, int n_gtgt, int n_tgt) {
    int i = blockIdx.x * blockDim.x + threadIdx.x;
    if (i < n_cur) {
        int x = coords[3 * i], y = coords[3 * i + 1], z = coords[3 * i + 2];
        if ((unsigned)x >= DIMV || (unsigned)y >= DIMV || (unsigned)z >= DIMV) return;
        int v = (x * DIMV + y) * DIMV + z;
        if (read_mask(occupancy, i, *mode_p)) out_mask[v] = 1.0f;
        if (cur_key[v] == i) {
#pragma unroll
            for (int c = 0; c < 6; ++c)
                __builtin_nontemporal_store(cur_vals4[i * 6 + c], &out_cur4[v * 6 + c]);
        }
        return;
    }
    int j = i - n_cur;
    if (j < n_glb) {
        if (o_valid[j] == 0.0f) return;
        int x = gcoords[3 * j]     - origin[0];
        int y = gcoords[3 * j + 1] - origin[1];
        int z = gcoords[3 * j + 2] - origin[2];
        int v = (x * DIMV + y) * DIMV + z;             // valid => in bounds
        out_mask[v] = 1.0f;
        if (glb_key[v] == j) {
#pragma unroll
            for (int c = 0; c < 6; ++c)
                __builtin_nontemporal_store(glb_vals4[j * 6 + c], &out_glb4[v * 6 + c]);
        }
        return;
    }
    int t = j - n_glb;
    if (t < n_gtgt) {
        int x = gt_coords[3 * t] - origin[0];
        int y = gt_coords[3 * t + 1] - origin[1];
        int z = gt_coords[3 * t + 2] - origin[2];
        if ((unsigned)x < DIMV && (unsigned)y < DIMV && (unsigned)z < DIMV) {
            int v = (x * DIMV + y) * DIMV + z;
            if (tgt_key[v] == t) out_tgt[v] = g_tsdf_tgt[t];
        }
        return;
    }
    int k = t - n_gtgt;
    if (k < n_tgt) {
        int x = ct_coords[3 * k], y = ct_coords[3 * k + 1], z = ct_coords[3 * k + 2];
        if ((unsigned)x < DIMV && (unsigned)y < DIMV && (unsigned)z < DIMV) {
            int v = (x * DIMV + y) * DIMV + z;
            if (tgt_key[v] == n_gtgt + k) out_tgt[v] = tsdf_tgt[k];
        }
    }
}

extern "C" void kernel_launch(void* const* d_in, const int* in_sizes, int n_in,
                              void* d_out, int out_size, void* d_ws, size_t ws_size,
                              hipStream_t stream) {
    const int*   current_coords  = (const int*)  d_in[0];
    const float* current_values  = (const float*)d_in[1];
    const int*   global_coords   = (const int*)  d_in[2];
    const float* global_value    = (const float*)d_in[3];
    const int*   coords_target   = (const int*)  d_in[4];   // local frame
    const float* tsdf_target     = (const float*)d_in[5];
    const int*   g_coords_target = (const int*)  d_in[6];   // global frame
    const float* g_tsdf_target   = (const float*)d_in[7];
    const int*   origin          = (const int*)  d_in[8];
    const void*  grid_mask       = d_in[9];
    const void*  occupancy       = d_in[10];

    const int n_cur  = in_sizes[0] / 3;   // 150000
    const int n_glb  = in_sizes[2] / 3;   // 300000
    const int n_tgt  = in_sizes[4] / 3;   // 100000
    const int n_gtgt = in_sizes[6] / 3;   // 200000

    // ---- workspace layout (~10.7 MB, 16B aligned) ----
    unsigned int* valid_bits = (unsigned int*)d_ws;          // WORDS u32 -> 0
    int*          cur_key    = (int*)(valid_bits + WORDS);   // NVOX int -> -1
    int*          glb_key    = cur_key + NVOX;
    int*          tgt_key    = glb_key + NVOX;
    int*          mode_p     = tgt_key + NVOX;

    // ---- output layout (flat concat, reference return order, float32) ----
    float* out     = (float*)d_out;
    float* o_mask  = out;                          // NVOX      (dense fill 0)
    float* o_cur   = o_mask + NVOX;                // NVOX*CCH  (dense fill 0)
    float* o_glb   = o_cur + NVOX * CCH;           // NVOX*CCH  (dense fill 0)
    float* o_tgt   = o_glb + NVOX * CCH;           // NVOX      (dense fill 1)
    float* o_valid = o_tgt + NVOX;                 // n_glb
    float* o_vtgt  = o_valid + n_glb;              // n_gtgt
    float* o_near  = o_vtgt + n_gtgt;              // n_glb

    init_detect_kernel<<<(N4I + 255) / 256, 256, 0, stream>>>(
        (v4i*)d_ws, (const unsigned int*)grid_mask, mode_p);

    const int sb = (n_cur + n_gtgt + n_tgt + 255) / 256;     // scatter blocks
    fill_scatter_kernel<<<sb + FILL_BLOCKS, 256, 0, stream>>>(
        (v4f*)o_mask,                      // dense region base (mask..tgt contiguous)
        current_coords, grid_mask, mode_p, valid_bits, cur_key,
        g_coords_target, coords_target, origin, tgt_key, o_vtgt,
        n_cur, n_gtgt, n_tgt, sb);

    scatter_global_kernel<<<(n_glb + 255) / 256, 256, 0, stream>>>(
        global_coords, origin, valid_bits, glb_key, o_valid, o_near, n_glb);

    winners_kernel<<<(n_cur + n_glb + n_gtgt + n_tgt + 255) / 256, 256, 0, stream>>>(
        (const v4f*)current_values, (const v4f*)global_value,
        current_coords, global_coords, g_coords_target, coords_target,
        tsdf_target, g_tsdf_target, occupancy, mode_p, origin,
        cur_key, glb_key, tgt_key, o_valid,
        o_mask, (v4f*)o_cur, (v4f*)o_glb, o_tgt,
        n_cur, n_glb, n_gtgt, n_tgt);
}

// Round 6
// 269.140 us; speedup vs baseline: 1.1506x; 1.1506x over previous
//
#include <hip/hip_runtime.h>

#define DIMV 96
#define CCH 24
#define NVOX (DIMV * DIMV * DIMV)        // 884736
#define HALFV (NVOX / 2)                 // 442368
#define WORDS (NVOX / 32)                // 27648 u32 bitmap words
#define ZERO_INTS (2 * WORDS)            // valid_bits + occ_bits -> zero-fill
#define TOTAL_INTS (ZERO_INTS + 3 * NVOX)// + key2 (2*NVOX) + tgt_key (NVOX) -> -1
#define N4I (TOTAL_INTS / 4)             // 677376 int4s (exact)
#define NZERO4 (ZERO_INTS / 4)           // 13824

// resolve launch geometry (all exact multiples of 256)
#define PAYLOAD_BLOCKS (HALFV * 6 / 256) // 10368
#define MASK_BLOCKS (NVOX / 1024)        // 864 (thread = 4 voxels)
#define TGT_BLOCKS (NVOX / 1024)         // 864
#define RESOLVE_BLOCKS (PAYLOAD_BLOCKS + MASK_BLOCKS + TGT_BLOCKS)

// Native clang vector types: __builtin_nontemporal_store requires these
// (HIP's float4/int4 are classes and get rejected).
typedef float v4f __attribute__((ext_vector_type(4)));
typedef int   v4i __attribute__((ext_vector_type(4)));
typedef int   v2i __attribute__((ext_vector_type(2)));

// ---------------------------------------------------------------------------
// K0: init workspace (vectorized) + mask-dtype detection (block 0).
// bool inputs may arrive as uint8 (raw numpy bool), int32, or float32:
//   int32 storage  -> words in {0,1}; float32 -> {0,0x3F800000}; uint8 -> other
// mode: 0 = uint8, 1 = int32, 2 = float32
// Keys MUST be explicitly -1: ws contents are unknown on the first call.
// ---------------------------------------------------------------------------
__global__ void init_detect_kernel(v4i* __restrict__ ws_vec,
                                   const unsigned int* __restrict__ mask_words,
                                   int* __restrict__ mode_p) {
    int i = blockIdx.x * blockDim.x + threadIdx.x;
    if (i < N4I) {
        int fill = (i < NZERO4) ? 0 : -1;
        v4i val = {fill, fill, fill, fill};
        ws_vec[i] = val;
    }
    if (blockIdx.x == 0) {
        __shared__ int s_byte, s_int, s_float;
        if (threadIdx.x == 0) { s_byte = 0; s_int = 0; s_float = 0; }
        __syncthreads();
        int flag = 0;
        for (int k = 0; k < 4; ++k) {                 // 256 thr x 4 = 1024 words
            unsigned int w = mask_words[threadIdx.x * 4 + k];
            if (w != 0u) {
                if (w == 1u)               flag |= 1;
                else if (w == 0x3F800000u) flag |= 2;
                else                       flag |= 4;
            }
        }
        if (flag & 1) atomicOr(&s_int, 1);
        if (flag & 2) atomicOr(&s_float, 1);
        if (flag & 4) atomicOr(&s_byte, 1);
        __syncthreads();
        if (threadIdx.x == 0)
            *mode_p = s_byte ? 0 : (s_float ? 2 : 1);
    }
}

__device__ __forceinline__ bool read_mask(const void* p, int i, int mode) {
    if (mode == 0) return ((const unsigned char*)p)[i] != 0;
    if (mode == 1) return ((const int*)p)[i] != 0;
    return ((const float*)p)[i] != 0.0f;
}

// ---------------------------------------------------------------------------
// K1: fused current rows + target rows (neither depends on valid_bits):
//   [0, n_cur): grid_mask -> valid bitmap, occupancy -> occ bitmap,
//     last-row-wins key atomicMax into key2[2v] (interleaved cur/glb keys).
//   [n_cur, +n_gtgt): global targets (shift by origin), tgt_key = j.
//   [.., +n_tgt): current-fragment targets, tgt_key = n_gtgt + k (current
//     beats global; later rows beat earlier -- torch cat order).
// ---------------------------------------------------------------------------
__global__ void scatter_cur_tgt_kernel(const int* __restrict__ coords,
                                       const void* __restrict__ grid_mask,
                                       const void* __restrict__ occupancy,
                                       const int* __restrict__ mode_p,
                                       unsigned int* __restrict__ valid_bits,
                                       unsigned int* __restrict__ occ_bits,
                                       int* __restrict__ key2,
                                       const int* __restrict__ gt_coords,
                                       const int* __restrict__ ct_coords,
                                       const int* __restrict__ origin,
                                       int* __restrict__ tgt_key,
                                       float* __restrict__ out_valid_target,
                                       int n_cur, int n_gtgt, int n_tgt) {
    int i = blockIdx.x * blockDim.x + threadIdx.x;
    if (i < n_cur) {
        int mode = *mode_p;
        int x = coords[3 * i], y = coords[3 * i + 1], z = coords[3 * i + 2];
        if ((unsigned)x >= DIMV || (unsigned)y >= DIMV || (unsigned)z >= DIMV) return;
        int v = (x * DIMV + y) * DIMV + z;
        if (read_mask(grid_mask, i, mode)) atomicOr(&valid_bits[v >> 5], 1u << (v & 31));
        if (read_mask(occupancy, i, mode)) atomicOr(&occ_bits[v >> 5], 1u << (v & 31));
        atomicMax(&key2[2 * v], i);                    // cur slot
        return;
    }
    int j = i - n_cur;
    if (j < n_gtgt) {
        int x = gt_coords[3 * j] - origin[0];
        int y = gt_coords[3 * j + 1] - origin[1];
        int z = gt_coords[3 * j + 2] - origin[2];
        bool inb = (unsigned)x < DIMV && (unsigned)y < DIMV && (unsigned)z < DIMV;
        out_valid_target[j] = inb ? 1.0f : 0.0f;
        if (inb) atomicMax(&tgt_key[(x * DIMV + y) * DIMV + z], j);
        return;
    }
    int k = j - n_gtgt;
    if (k < n_tgt) {
        int x = ct_coords[3 * k], y = ct_coords[3 * k + 1], z = ct_coords[3 * k + 2];
        if ((unsigned)x < DIMV && (unsigned)y < DIMV && (unsigned)z < DIMV)
            atomicMax(&tgt_key[(x * DIMV + y) * DIMV + z], n_gtgt + k);
    }
}

// ---------------------------------------------------------------------------
// K2: global rows: shift by origin, in-bounds, gather visibility bit (110 KB
// bitmap, L2-hot), write per-row valid/near floats, glb key -> key2[2v+1].
// ---------------------------------------------------------------------------
__global__ void scatter_global_kernel(const int* __restrict__ gcoords,
                                      const int* __restrict__ origin,
                                      const unsigned int* __restrict__ valid_bits,
                                      int* __restrict__ key2,
                                      float* __restrict__ out_valid,
                                      float* __restrict__ out_near,
                                      int n) {
    int i = blockIdx.x * blockDim.x + threadIdx.x;
    if (i >= n) return;
    int x = gcoords[3 * i]     - origin[0];
    int y = gcoords[3 * i + 1] - origin[1];
    int z = gcoords[3 * i + 2] - origin[2];
    bool inb = (unsigned)x < DIMV && (unsigned)y < DIMV && (unsigned)z < DIMV;
    bool valid = false;
    if (inb) {
        int v = (x * DIMV + y) * DIMV + z;
        valid = (valid_bits[v >> 5] >> (v & 31)) & 1u;
        if (valid) atomicMax(&key2[2 * v + 1], i);     // glb slot
    }
    out_valid[i] = valid ? 1.0f : 0.0f;
    out_near[i]  = (inb && !valid) ? 1.0f : 0.0f;
}

// ---------------------------------------------------------------------------
// K3: resolve v4, three block roles in one launch:
//  payload blocks [0,PB): thread = (voxel-pair p, c4). v0=p, v1=p+HALFV.
//    One int2 key load per voxel ({cur,glb} interleaved), 4 independent 16B
//    gathers, 4 NT stores (lane-contiguous: v0 stream at idx, v1 stream at
//    idx+HALFV*6). No divergent tail.
//  mask blocks: thread = 4 consecutive voxels: two v4i key2 loads -> glb keys,
//    one occ word; v4f NT store. updated_mask == (glb_key>=0)||occ (Gaussian
//    rows are never all-zero).
//  tgt blocks: thread = 4 voxels: v4i tgt_key load, sparse 4B winner gathers,
//    v4f NT store.
// ---------------------------------------------------------------------------
__global__ void resolve_kernel(const v4f* __restrict__ cur_vals4,
                               const v4f* __restrict__ glb_vals4,
                               const float* __restrict__ tsdf_tgt,
                               const float* __restrict__ g_tsdf_tgt,
                               const v2i* __restrict__ key2_2,
                               const v4i* __restrict__ key2_4,
                               const v4i* __restrict__ tgt_key4,
                               const unsigned int* __restrict__ occ_bits,
                               v4f* __restrict__ out_mask4,
                               v4f* __restrict__ out_cur4,
                               v4f* __restrict__ out_glb4,
                               v4f* __restrict__ out_tgt4,
                               int n_gtgt) {
    int b = blockIdx.x;
    if (b < PAYLOAD_BLOCKS) {
        int idx = b * 256 + threadIdx.x;               // [0, HALFV*6)
        int p  = idx / 6;
        int c4 = idx - p * 6;
        int v0 = p, v1 = p + HALFV;

        v2i k0 = key2_2[v0];                           // {ck0, gk0} one 8B load
        v2i k1 = key2_2[v1];                           // {ck1, gk1}

        v4f z = {0.f, 0.f, 0.f, 0.f};
        v4f a0 = (k0.x >= 0) ? cur_vals4[k0.x * 6 + c4] : z;
        v4f a1 = (k1.x >= 0) ? cur_vals4[k1.x * 6 + c4] : z;
        v4f b0 = (k0.y >= 0) ? glb_vals4[k0.y * 6 + c4] : z;
        v4f b1 = (k1.y >= 0) ? glb_vals4[k1.y * 6 + c4] : z;

        __builtin_nontemporal_store(a0, &out_cur4[idx]);            // == v0*6+c4
        __builtin_nontemporal_store(a1, &out_cur4[idx + HALFV * 6]);
        __builtin_nontemporal_store(b0, &out_glb4[idx]);
        __builtin_nontemporal_store(b1, &out_glb4[idx + HALFV * 6]);
        return;
    }
    if (b < PAYLOAD_BLOCKS + MASK_BLOCKS) {
        int t = (b - PAYLOAD_BLOCKS) * 256 + threadIdx.x;  // [0, NVOX/4)
        int v = 4 * t;
        v4i A = key2_4[2 * t];                         // {ck[v],gk[v],ck[v+1],gk[v+1]}
        v4i B = key2_4[2 * t + 1];
        unsigned int occw = occ_bits[v >> 5] >> (v & 31);  // bits 0..3 valid
        v4f m;
        m.x = (A.y >= 0 || (occw & 1u)) ? 1.0f : 0.0f;
        m.y = (A.w >= 0 || ((occw >> 1) & 1u)) ? 1.0f : 0.0f;
        m.z = (B.y >= 0 || ((occw >> 2) & 1u)) ? 1.0f : 0.0f;
        m.w = (B.w >= 0 || ((occw >> 3) & 1u)) ? 1.0f : 0.0f;
        __builtin_nontemporal_store(m, &out_mask4[t]);
        return;
    }
    {
        int t = (b - PAYLOAD_BLOCKS - MASK_BLOCKS) * 256 + threadIdx.x;
        v4i T = tgt_key4[t];
        v4f r;
        r.x = (T.x < 0) ? 1.0f : (T.x >= n_gtgt ? tsdf_tgt[T.x - n_gtgt] : g_tsdf_tgt[T.x]);
        r.y = (T.y < 0) ? 1.0f : (T.y >= n_gtgt ? tsdf_tgt[T.y - n_gtgt] : g_tsdf_tgt[T.y]);
        r.z = (T.z < 0) ? 1.0f : (T.z >= n_gtgt ? tsdf_tgt[T.z - n_gtgt] : g_tsdf_tgt[T.z]);
        r.w = (T.w < 0) ? 1.0f : (T.w >= n_gtgt ? tsdf_tgt[T.w - n_gtgt] : g_tsdf_tgt[T.w]);
        __builtin_nontemporal_store(r, &out_tgt4[t]);
    }
}

extern "C" void kernel_launch(void* const* d_in, const int* in_sizes, int n_in,
                              void* d_out, int out_size, void* d_ws, size_t ws_size,
                              hipStream_t stream) {
    const int*   current_coords  = (const int*)  d_in[0];
    const float* current_values  = (const float*)d_in[1];
    const int*   global_coords   = (const int*)  d_in[2];
    const float* global_value    = (const float*)d_in[3];
    const int*   coords_target   = (const int*)  d_in[4];   // local frame
    const float* tsdf_target     = (const float*)d_in[5];
    const int*   g_coords_target = (const int*)  d_in[6];   // global frame
    const float* g_tsdf_target   = (const float*)d_in[7];
    const int*   origin          = (const int*)  d_in[8];
    const void*  grid_mask       = d_in[9];
    const void*  occupancy       = d_in[10];

    const int n_cur  = in_sizes[0] / 3;   // 150000
    const int n_glb  = in_sizes[2] / 3;   // 300000
    const int n_tgt  = in_sizes[4] / 3;   // 100000
    const int n_gtgt = in_sizes[6] / 3;   // 200000

    // ---- workspace layout (~10.8 MB, 16B aligned) ----
    unsigned int* valid_bits = (unsigned int*)d_ws;          // WORDS u32 -> 0
    unsigned int* occ_bits   = valid_bits + WORDS;           // WORDS u32 -> 0
    int*          key2       = (int*)(occ_bits + WORDS);     // 2*NVOX int -> -1 (cur,glb interleaved)
    int*          tgt_key    = key2 + 2 * NVOX;              // NVOX int -> -1
    int*          mode_p     = tgt_key + NVOX;

    // ---- output layout (flat concat, reference return order, float32) ----
    float* out     = (float*)d_out;
    float* o_mask  = out;                          // NVOX
    float* o_cur   = o_mask + NVOX;                // NVOX*CCH
    float* o_glb   = o_cur + NVOX * CCH;           // NVOX*CCH
    float* o_tgt   = o_glb + NVOX * CCH;           // NVOX
    float* o_valid = o_tgt + NVOX;                 // n_glb
    float* o_vtgt  = o_valid + n_glb;              // n_gtgt
    float* o_near  = o_vtgt + n_gtgt;              // n_glb

    init_detect_kernel<<<(N4I + 255) / 256, 256, 0, stream>>>(
        (v4i*)d_ws, (const unsigned int*)grid_mask, mode_p);

    scatter_cur_tgt_kernel<<<(n_cur + n_gtgt + n_tgt + 255) / 256, 256, 0, stream>>>(
        current_coords, grid_mask, occupancy, mode_p, valid_bits, occ_bits, key2,
        g_coords_target, coords_target, origin, tgt_key, o_vtgt,
        n_cur, n_gtgt, n_tgt);

    scatter_global_kernel<<<(n_glb + 255) / 256, 256, 0, stream>>>(
        global_coords, origin, valid_bits, key2, o_valid, o_near, n_glb);

    resolve_kernel<<<RESOLVE_BLOCKS, 256, 0, stream>>>(
        (const v4f*)current_values, (const v4f*)global_value,
        tsdf_target, g_tsdf_target,
        (const v2i*)key2, (const v4i*)key2, (const v4i*)tgt_key, occ_bits,
        (v4f*)o_mask, (v4f*)o_cur, (v4f*)o_glb, (v4f*)o_tgt, n_gtgt);
}

// Round 7
// 267.226 us; speedup vs baseline: 1.1588x; 1.0072x over previous
//
#include <hip/hip_runtime.h>

#define DIMV 96
#define CCH 24
#define NVOX (DIMV * DIMV * DIMV)        // 884736
#define HALFV (NVOX / 2)                 // 442368
#define WORDS (NVOX / 32)                // 27648 u32 bitmap words
#define ZERO_INTS (2 * WORDS)            // valid_bits + occ_bits -> zero-fill
#define TOTAL_INTS (ZERO_INTS + 3 * NVOX)// + key2 (2*NVOX) + tgt_key (NVOX) -> -1
#define N4I (TOTAL_INTS / 4)             // 677376 int4s (exact)
#define NZERO4 (ZERO_INTS / 4)           // 13824

// resolve launch geometry (all exact multiples of 256)
#define PAYLOAD_BLOCKS (HALFV * 6 / 256) // 10368
#define MT_BLOCKS (NVOX / 1024)          // 864 (thread = 4 voxels, mask+tgt fused)
#define RESOLVE_BLOCKS (PAYLOAD_BLOCKS + MT_BLOCKS)

// Native clang vector types: __builtin_nontemporal_* requires these
// (HIP's float4/int4 are classes and get rejected).
typedef float v4f __attribute__((ext_vector_type(4)));
typedef int   v4i __attribute__((ext_vector_type(4)));
typedef int   v2i __attribute__((ext_vector_type(2)));

// ---------------------------------------------------------------------------
// K0: init workspace (vectorized) + mask-dtype detection (block 0).
// bool inputs may arrive as uint8 (raw numpy bool), int32, or float32:
//   int32 storage  -> words in {0,1}; float32 -> {0,0x3F800000}; uint8 -> other
// mode: 0 = uint8, 1 = int32, 2 = float32
// Keys MUST be explicitly -1: ws contents are unknown on the first call.
// ---------------------------------------------------------------------------
__global__ void init_detect_kernel(v4i* __restrict__ ws_vec,
                                   const unsigned int* __restrict__ mask_words,
                                   int* __restrict__ mode_p) {
    int i = blockIdx.x * blockDim.x + threadIdx.x;
    if (i < N4I) {
        int fill = (i < NZERO4) ? 0 : -1;
        v4i val = {fill, fill, fill, fill};
        ws_vec[i] = val;
    }
    if (blockIdx.x == 0) {
        __shared__ int s_byte, s_int, s_float;
        if (threadIdx.x == 0) { s_byte = 0; s_int = 0; s_float = 0; }
        __syncthreads();
        int flag = 0;
        for (int k = 0; k < 4; ++k) {                 // 256 thr x 4 = 1024 words
            unsigned int w = mask_words[threadIdx.x * 4 + k];
            if (w != 0u) {
                if (w == 1u)               flag |= 1;
                else if (w == 0x3F800000u) flag |= 2;
                else                       flag |= 4;
            }
        }
        if (flag & 1) atomicOr(&s_int, 1);
        if (flag & 2) atomicOr(&s_float, 1);
        if (flag & 4) atomicOr(&s_byte, 1);
        __syncthreads();
        if (threadIdx.x == 0)
            *mode_p = s_byte ? 0 : (s_float ? 2 : 1);
    }
}

__device__ __forceinline__ bool read_mask(const void* p, int i, int mode) {
    if (mode == 0) return ((const unsigned char*)p)[i] != 0;
    if (mode == 1) return ((const int*)p)[i] != 0;
    return ((const float*)p)[i] != 0.0f;
}

// ---------------------------------------------------------------------------
// K1: fused current rows + target rows (neither depends on valid_bits):
//   [0, n_cur): grid_mask -> valid bitmap, occupancy -> occ bitmap,
//     last-row-wins key atomicMax into key2[2v] (interleaved cur/glb keys).
//   [n_cur, +n_gtgt): global targets (shift by origin), tgt_key = j.
//   [.., +n_tgt): current-fragment targets, tgt_key = n_gtgt + k (current
//     beats global; later rows beat earlier -- torch cat order).
// ---------------------------------------------------------------------------
__global__ void scatter_cur_tgt_kernel(const int* __restrict__ coords,
                                       const void* __restrict__ grid_mask,
                                       const void* __restrict__ occupancy,
                                       const int* __restrict__ mode_p,
                                       unsigned int* __restrict__ valid_bits,
                                       unsigned int* __restrict__ occ_bits,
                                       int* __restrict__ key2,
                                       const int* __restrict__ gt_coords,
                                       const int* __restrict__ ct_coords,
                                       const int* __restrict__ origin,
                                       int* __restrict__ tgt_key,
                                       float* __restrict__ out_valid_target,
                                       int n_cur, int n_gtgt, int n_tgt) {
    int i = blockIdx.x * blockDim.x + threadIdx.x;
    if (i < n_cur) {
        int mode = *mode_p;
        int x = coords[3 * i], y = coords[3 * i + 1], z = coords[3 * i + 2];
        if ((unsigned)x >= DIMV || (unsigned)y >= DIMV || (unsigned)z >= DIMV) return;
        int v = (x * DIMV + y) * DIMV + z;
        if (read_mask(grid_mask, i, mode)) atomicOr(&valid_bits[v >> 5], 1u << (v & 31));
        if (read_mask(occupancy, i, mode)) atomicOr(&occ_bits[v >> 5], 1u << (v & 31));
        atomicMax(&key2[2 * v], i);                    // cur slot
        return;
    }
    int j = i - n_cur;
    if (j < n_gtgt) {
        int x = gt_coords[3 * j] - origin[0];
        int y = gt_coords[3 * j + 1] - origin[1];
        int z = gt_coords[3 * j + 2] - origin[2];
        bool inb = (unsigned)x < DIMV && (unsigned)y < DIMV && (unsigned)z < DIMV;
        __builtin_nontemporal_store(inb ? 1.0f : 0.0f, &out_valid_target[j]);
        if (inb) atomicMax(&tgt_key[(x * DIMV + y) * DIMV + z], j);
        return;
    }
    int k = j - n_gtgt;
    if (k < n_tgt) {
        int x = ct_coords[3 * k], y = ct_coords[3 * k + 1], z = ct_coords[3 * k + 2];
        if ((unsigned)x < DIMV && (unsigned)y < DIMV && (unsigned)z < DIMV)
            atomicMax(&tgt_key[(x * DIMV + y) * DIMV + z], n_gtgt + k);
    }
}

// ---------------------------------------------------------------------------
// K2: global rows: shift by origin, in-bounds, gather visibility bit (110 KB
// bitmap, L2-hot), write per-row valid/near floats (NT), glb key -> key2[2v+1].
// ---------------------------------------------------------------------------
__global__ void scatter_global_kernel(const int* __restrict__ gcoords,
                                      const int* __restrict__ origin,
                                      const unsigned int* __restrict__ valid_bits,
                                      int* __restrict__ key2,
                                      float* __restrict__ out_valid,
                                      float* __restrict__ out_near,
                                      int n) {
    int i = blockIdx.x * blockDim.x + threadIdx.x;
    if (i >= n) return;
    int x = gcoords[3 * i]     - origin[0];
    int y = gcoords[3 * i + 1] - origin[1];
    int z = gcoords[3 * i + 2] - origin[2];
    bool inb = (unsigned)x < DIMV && (unsigned)y < DIMV && (unsigned)z < DIMV;
    bool valid = false;
    if (inb) {
        int v = (x * DIMV + y) * DIMV + z;
        valid = (valid_bits[v >> 5] >> (v & 31)) & 1u;
        if (valid) atomicMax(&key2[2 * v + 1], i);     // glb slot
    }
    __builtin_nontemporal_store(valid ? 1.0f : 0.0f, &out_valid[i]);
    __builtin_nontemporal_store((inb && !valid) ? 1.0f : 0.0f, &out_near[i]);
}

// ---------------------------------------------------------------------------
// K3: resolve, two block roles in one launch:
//  payload blocks [0,PB): thread = (voxel-pair p, c4). v0=p, v1=p+HALFV.
//    One int2 key load per voxel ({cur,glb} interleaved; L2-cacheable — key2
//    is re-read by the mt role), 4 independent 16B NT gathers (value tables
//    are read-once: bypass L2 retention), 4 NT stores (lane-contiguous).
//  mt blocks: thread = 4 consecutive voxels: two v4i key2 loads (glb keys) +
//    occ word -> mask4; v4i tgt_key load + sparse 4B winner gathers -> tgt4.
//    updated_mask == (glb_key>=0)||occ (Gaussian rows never all-zero).
// ---------------------------------------------------------------------------
__global__ void resolve_kernel(const v4f* __restrict__ cur_vals4,
                               const v4f* __restrict__ glb_vals4,
                               const float* __restrict__ tsdf_tgt,
                               const float* __restrict__ g_tsdf_tgt,
                               const v2i* __restrict__ key2_2,
                               const v4i* __restrict__ key2_4,
                               const v4i* __restrict__ tgt_key4,
                               const unsigned int* __restrict__ occ_bits,
                               v4f* __restrict__ out_mask4,
                               v4f* __restrict__ out_cur4,
                               v4f* __restrict__ out_glb4,
                               v4f* __restrict__ out_tgt4,
                               int n_gtgt) {
    int b = blockIdx.x;
    if (b < PAYLOAD_BLOCKS) {
        int idx = b * 256 + threadIdx.x;               // [0, HALFV*6)
        int p  = idx / 6;
        int c4 = idx - p * 6;
        int v0 = p, v1 = p + HALFV;

        v2i k0 = key2_2[v0];                           // {ck0, gk0} one 8B load
        v2i k1 = key2_2[v1];                           // {ck1, gk1}

        v4f z = {0.f, 0.f, 0.f, 0.f};
        v4f a0 = (k0.x >= 0) ? __builtin_nontemporal_load(&cur_vals4[k0.x * 6 + c4]) : z;
        v4f a1 = (k1.x >= 0) ? __builtin_nontemporal_load(&cur_vals4[k1.x * 6 + c4]) : z;
        v4f b0 = (k0.y >= 0) ? __builtin_nontemporal_load(&glb_vals4[k0.y * 6 + c4]) : z;
        v4f b1 = (k1.y >= 0) ? __builtin_nontemporal_load(&glb_vals4[k1.y * 6 + c4]) : z;

        __builtin_nontemporal_store(a0, &out_cur4[idx]);            // == v0*6+c4
        __builtin_nontemporal_store(a1, &out_cur4[idx + HALFV * 6]);
        __builtin_nontemporal_store(b0, &out_glb4[idx]);
        __builtin_nontemporal_store(b1, &out_glb4[idx + HALFV * 6]);
        return;
    }
    {
        int t = (b - PAYLOAD_BLOCKS) * 256 + threadIdx.x;  // [0, NVOX/4)
        int v = 4 * t;
        v4i A = key2_4[2 * t];                         // {ck[v],gk[v],ck[v+1],gk[v+1]}
        v4i B = key2_4[2 * t + 1];
        v4i T = tgt_key4[t];
        unsigned int occw = occ_bits[v >> 5] >> (v & 31);  // bits 0..3 valid
        v4f m;
        m.x = (A.y >= 0 || (occw & 1u)) ? 1.0f : 0.0f;
        m.y = (A.w >= 0 || ((occw >> 1) & 1u)) ? 1.0f : 0.0f;
        m.z = (B.y >= 0 || ((occw >> 2) & 1u)) ? 1.0f : 0.0f;
        m.w = (B.w >= 0 || ((occw >> 3) & 1u)) ? 1.0f : 0.0f;
        v4f r;
        r.x = (T.x < 0) ? 1.0f : (T.x >= n_gtgt ? tsdf_tgt[T.x - n_gtgt] : g_tsdf_tgt[T.x]);
        r.y = (T.y < 0) ? 1.0f : (T.y >= n_gtgt ? tsdf_tgt[T.y - n_gtgt] : g_tsdf_tgt[T.y]);
        r.z = (T.z < 0) ? 1.0f : (T.z >= n_gtgt ? tsdf_tgt[T.z - n_gtgt] : g_tsdf_tgt[T.z]);
        r.w = (T.w < 0) ? 1.0f : (T.w >= n_gtgt ? tsdf_tgt[T.w - n_gtgt] : g_tsdf_tgt[T.w]);
        __builtin_nontemporal_store(m, &out_mask4[t]);
        __builtin_nontemporal_store(r, &out_tgt4[t]);
    }
}

extern "C" void kernel_launch(void* const* d_in, const int* in_sizes, int n_in,
                              void* d_out, int out_size, void* d_ws, size_t ws_size,
                              hipStream_t stream) {
    const int*   current_coords  = (const int*)  d_in[0];
    const float* current_values  = (const float*)d_in[1];
    const int*   global_coords   = (const int*)  d_in[2];
    const float* global_value    = (const float*)d_in[3];
    const int*   coords_target   = (const int*)  d_in[4];   // local frame
    const float* tsdf_target     = (const float*)d_in[5];
    const int*   g_coords_target = (const int*)  d_in[6];   // global frame
    const float* g_tsdf_target   = (const float*)d_in[7];
    const int*   origin          = (const int*)  d_in[8];
    const void*  grid_mask       = d_in[9];
    const void*  occupancy       = d_in[10];

    const int n_cur  = in_sizes[0] / 3;   // 150000
    const int n_glb  = in_sizes[2] / 3;   // 300000
    const int n_tgt  = in_sizes[4] / 3;   // 100000
    const int n_gtgt = in_sizes[6] / 3;   // 200000

    // ---- workspace layout (~10.8 MB, 16B aligned) ----
    unsigned int* valid_bits = (unsigned int*)d_ws;          // WORDS u32 -> 0
    unsigned int* occ_bits   = valid_bits + WORDS;           // WORDS u32 -> 0
    int*          key2       = (int*)(occ_bits + WORDS);     // 2*NVOX int -> -1 (cur,glb interleaved)
    int*          tgt_key    = key2 + 2 * NVOX;              // NVOX int -> -1
    int*          mode_p     = tgt_key + NVOX;

    // ---- output layout (flat concat, reference return order, float32) ----
    float* out     = (float*)d_out;
    float* o_mask  = out;                          // NVOX
    float* o_cur   = o_mask + NVOX;                // NVOX*CCH
    float* o_glb   = o_cur + NVOX * CCH;           // NVOX*CCH
    float* o_tgt   = o_glb + NVOX * CCH;           // NVOX
    float* o_valid = o_tgt + NVOX;                 // n_glb
    float* o_vtgt  = o_valid + n_glb;              // n_gtgt
    float* o_near  = o_vtgt + n_gtgt;              // n_glb

    init_detect_kernel<<<(N4I + 255) / 256, 256, 0, stream>>>(
        (v4i*)d_ws, (const unsigned int*)grid_mask, mode_p);

    scatter_cur_tgt_kernel<<<(n_cur + n_gtgt + n_tgt + 255) / 256, 256, 0, stream>>>(
        current_coords, grid_mask, occupancy, mode_p, valid_bits, occ_bits, key2,
        g_coords_target, coords_target, origin, tgt_key, o_vtgt,
        n_cur, n_gtgt, n_tgt);

    scatter_global_kernel<<<(n_glb + 255) / 256, 256, 0, stream>>>(
        global_coords, origin, valid_bits, key2, o_valid, o_near, n_glb);

    resolve_kernel<<<RESOLVE_BLOCKS, 256, 0, stream>>>(
        (const v4f*)current_values, (const v4f*)global_value,
        tsdf_target, g_tsdf_target,
        (const v2i*)key2, (const v4i*)key2, (const v4i*)tgt_key, occ_bits,
        (v4f*)o_mask, (v4f*)o_cur, (v4f*)o_glb, (v4f*)o_tgt, n_gtgt);
}